// Round 2
// baseline (343.030 us; speedup 1.0000x reference)
//
#include <hip/hip_runtime.h>

typedef unsigned short u16;
using u16x4  = __attribute__((ext_vector_type(4))) unsigned short;
using u16x8  = __attribute__((ext_vector_type(8))) unsigned short;
using bf16x8 = __attribute__((ext_vector_type(8))) short;
using f32x4  = __attribute__((ext_vector_type(4))) float;
using f32x16 = __attribute__((ext_vector_type(16))) float;

// ---------- helpers ----------
__device__ __forceinline__ u16 f2bf(float f) {
  union { float f; unsigned u; } v; v.f = f;
  unsigned r = v.u + 0x7FFFu + ((v.u >> 16) & 1u);  // RNE (inputs bounded, no NaN)
  return (u16)(r >> 16);
}

__device__ __forceinline__ unsigned cvt_pk_bf16(float a, float b) {
  unsigned d;
  asm("v_cvt_pk_bf16_f32 %0, %1, %2" : "=v"(d) : "v"(a), "v"(b));
  return d;  // low16 = bf16(a), high16 = bf16(b)
}

// ---------- fused pre-pass: W transpose+convert AND x convert ----------
// blocks 0..8191: W [mat][i][h] fp32 -> blocked bf16 [mat][i/16][h][16]
//   element (i,h) -> (i>>4)*4096 + h*16 + (i&15)
// blocks 8192..8703: x fp32 -> bf16 (512 blocks x 256 thr x float4 == |x|/4)
__global__ __launch_bounds__(256) void prepass_k(
    const float* __restrict__ W1, const float* __restrict__ W2,
    u16* __restrict__ w1t, u16* __restrict__ w2t,
    const float* __restrict__ x, u16* __restrict__ xb) {
  __shared__ float tile[64][65];
  const int bid = blockIdx.x;
  const int t = threadIdx.x;
  if (bid >= 8192) {                   // x conversion
    int i = (bid - 8192) * 256 + t;
    float4 v = ((const float4*)x)[i];
    u16x4 u;
    u.x = f2bf(v.x); u.y = f2bf(v.y); u.z = f2bf(v.z); u.w = f2bf(v.w);
    ((u16x4*)xb)[i] = u;
    return;
  }
  const int mat = bid >> 4;
  const int tl  = bid & 15;
  const int i0 = (tl >> 2) * 64, h0 = (tl & 3) * 64;
  const float* src = (mat < 256) ? (W1 + mat * 65536) : (W2 + (mat - 256) * 65536);
  u16*       dst   = (mat < 256) ? (w1t + mat * 65536) : (w2t + (mat - 256) * 65536);
#pragma unroll
  for (int j = 0; j < 4; ++j) {
    int lin = j * 256 + t;
    int row = lin >> 4, c4 = lin & 15;
    float4 v = *(const float4*)(src + (i0 + row) * 256 + h0 + c4 * 4);
    tile[row][c4 * 4 + 0] = v.x; tile[row][c4 * 4 + 1] = v.y;
    tile[row][c4 * 4 + 2] = v.z; tile[row][c4 * 4 + 3] = v.w;
  }
  __syncthreads();
  const int col = t >> 2;            // h = h0 + col
  const int kk  = (t & 3) * 8;       // 0,8,16,24
#pragma unroll
  for (int p = 0; p < 2; ++p) {      // two 32-row sub-stripes per 64-row tile
    u16x8 o;
#pragma unroll
    for (int jj = 0; jj < 8; ++jj)
      o[jj] = f2bf(tile[p * 32 + kk + jj][col]);
    *(u16x8*)(dst + ((i0 >> 4) + 2 * p + (kk >> 4)) * 4096 + (h0 + col) * 16 + (kk & 8)) = o;
  }
}

// ---------- main fused kernel (transposed formulation, 32x32x16 MFMA) ----------
// Block = (subcarrier c, 128-row batch tile). 512 threads = 8 waves = 2 wq x 4 bh.
// Wave: 4 m-frags (out-cols m_base=wq*128, +0/32/64/96) x 1 n-frag (batch rows bh*32).
// 4x B-reuse per LDS read: 1 ds_read_b128 feeds 4 MFMAs (was 2 reads / 4 MFMAs).
// A = W^T from global (blocked layout, b128, L1/L2-resident via same-block redundancy),
// B = x/H1 rows from LDS row-major (stride 264).
// C/D: col(lane&31)=batch row, row(reg)=out-col -> all epilogues in-lane.
// Regs: 64 AGPR acc + ~56 VGPR -> 4 waves/SIMD, 2 blocks/CU (LDS 69.6 KB).
__global__ __launch_bounds__(512, 4) void rf_main_k(
    const u16* __restrict__ xb, const u16* __restrict__ w1t, const u16* __restrict__ w2t,
    const float* __restrict__ b1, const float* __restrict__ b2,
    const float* __restrict__ w3, const float* __restrict__ b3,
    float* __restrict__ out) {
  __shared__ u16 sH[128 * 264];        // x-tile, then H1 (in place), stride 264
  __shared__ float red[4 * 128];       // (wq*2+hi) x 128 rows

  const int bid  = blockIdx.x;
  const int xcd  = bid & 7;
  const int j8   = bid >> 3;
  const int c    = xcd * 32 + (j8 >> 4);
  const int b0   = (j8 & 15) * 128;
  const int t    = threadIdx.x;
  const int lane = t & 63;
  const int w    = t >> 6;
  const int l31  = lane & 31;
  const int hi   = lane >> 5;
  const bool hiH = hi != 0;
  const int wq   = w & 1;
  const int bh   = w >> 1;
  const int m_base = wq * 128;
  const int n_base = bh * 32;

  const u16* w1c = w1t + c * 65536;
  const u16* w2c = w2t + c * 65536;
  // A (weights, global): + ch*4096 + mi*512
  const int aoff = (m_base + l31) * 16 + hi * 8;
  // B (x/H1, LDS): + ch*16
  const int bbase = (n_base + l31) * 264 + hi * 8;
  // wave-uniform column base for bias/w3 scalar loads
  const int bidx = __builtin_amdgcn_readfirstlane(c * 256 + m_base);

  f32x16 acc[4];
  bf16x8 aA[4], aB[4];

#define LOADA(dst, base)                                         \
  { _Pragma("unroll")                                            \
    for (int _mi = 0; _mi < 4; ++_mi)                            \
      dst[_mi] = *(const bf16x8*)((base) + _mi * 512); }

#define COMPUTE(fr, ch)                                          \
  { bf16x8 _b = *(const bf16x8*)&sH[bbase + (ch) * 16];          \
    acc[0] = __builtin_amdgcn_mfma_f32_32x32x16_bf16(fr[0], _b, acc[0], 0, 0, 0); \
    acc[1] = __builtin_amdgcn_mfma_f32_32x32x16_bf16(fr[1], _b, acc[1], 0, 0, 0); \
    acc[2] = __builtin_amdgcn_mfma_f32_32x32x16_bf16(fr[2], _b, acc[2], 0, 0, 0); \
    acc[3] = __builtin_amdgcn_mfma_f32_32x32x16_bf16(fr[3], _b, acc[3], 0, 0, 0); }

  // acc init = bias (wave-uniform per reg up to the hi/lo half-wave select)
#define INIT_ACC(bp)                                             \
  { _Pragma("unroll")                                            \
    for (int _mi = 0; _mi < 4; ++_mi) {                          \
      _Pragma("unroll")                                          \
      for (int _g = 0; _g < 4; ++_g) {                           \
        f32x4 _lo = *(const f32x4*)((bp) + bidx + _mi * 32 + _g * 8);     \
        f32x4 _h4 = *(const f32x4*)((bp) + bidx + _mi * 32 + _g * 8 + 4); \
        _Pragma("unroll")                                        \
        for (int _r = 0; _r < 4; ++_r)                           \
          acc[_mi][_g * 4 + _r] = hiH ? _h4[_r] : _lo[_r];       \
      } } }

  // prefetch W1 chunk 0 while staging x
  LOADA(aA, w1c + aoff);

  // stage x-tile: 128 rows x 256 u16 -> sH stride 264
#pragma unroll
  for (int i = 0; i < 8; ++i) {
    int flat = i * 512 + t;
    int r = flat >> 5, s = flat & 31;
    u16x8 g = *(const u16x8*)(xb + (b0 + r) * 256 + s * 8);
    *(u16x8*)&sH[r * 264 + s * 8] = g;
  }
  INIT_ACC(b1);
  __syncthreads();

  // ========== Phase A: H1^T = W1^T . x^T (+b1, relu), barrier-free K-loop ==========
#pragma unroll 1
  for (int ch = 0; ch < 16; ch += 2) {
    LOADA(aB, w1c + (ch + 1) * 4096 + aoff);
    COMPUTE(aA, ch);
    const u16* nxt = (ch == 14) ? (w2c + aoff)
                                : (w1c + (ch + 2) * 4096 + aoff);
    LOADA(aA, nxt);
    COMPUTE(aB, ch + 1);
  }

  // Phase A epilogue: relu -> bf16 H1, in place over sX (b64 stores, in-lane packing)
  __syncthreads();                     // all x reads retired
  {
    const int row = n_base + l31;
#pragma unroll
    for (int mi = 0; mi < 4; ++mi)
#pragma unroll
      for (int g = 0; g < 4; ++g) {
        float v0 = fmaxf(acc[mi][g * 4 + 0], 0.f);
        float v1 = fmaxf(acc[mi][g * 4 + 1], 0.f);
        float v2 = fmaxf(acc[mi][g * 4 + 2], 0.f);
        float v3 = fmaxf(acc[mi][g * 4 + 3], 0.f);
        uint2 p;
        p.x = cvt_pk_bf16(v0, v1);
        p.y = cvt_pk_bf16(v2, v3);
        *(uint2*)&sH[row * 264 + m_base + mi * 32 + g * 8 + 4 * hi] = p;
      }
  }
  INIT_ACC(b2);
  __syncthreads();                     // H1 published

  // ========== Phase B: H2^T = W2^T . H1^T (+b2, relu), then in-lane dot W3 ==========
#pragma unroll 1
  for (int ch = 0; ch < 16; ch += 2) {
    LOADA(aB, w2c + (ch + 1) * 4096 + aoff);
    COMPUTE(aA, ch);
    if (ch < 14) LOADA(aA, w2c + (ch + 2) * 4096 + aoff);
    COMPUTE(aB, ch + 1);
  }

  // Phase B epilogue: out-col reduction fully in-lane (w3 wave-uniform per reg)
  float part = 0.f;
#pragma unroll
  for (int mi = 0; mi < 4; ++mi)
#pragma unroll
    for (int g = 0; g < 4; ++g) {
      f32x4 wlo = *(const f32x4*)(w3 + bidx + mi * 32 + g * 8);
      f32x4 whi = *(const f32x4*)(w3 + bidx + mi * 32 + g * 8 + 4);
#pragma unroll
      for (int r = 0; r < 4; ++r) {
        float wv = hiH ? whi[r] : wlo[r];
        part += fmaxf(acc[mi][g * 4 + r], 0.f) * wv;
      }
    }
  red[(wq * 2 + hi) * 128 + n_base + l31] = part;
  __syncthreads();
  if (t < 128) {
    float v = b3[c];
#pragma unroll
    for (int k = 0; k < 4; ++k) v += red[k * 128 + t];
    out[(b0 + t) * 256 + c] = v;
  }
#undef LOADA
#undef COMPUTE
#undef INIT_ACC
}

// ---------- launcher ----------
extern "C" void kernel_launch(void* const* d_in, const int* in_sizes, int n_in,
                              void* d_out, int out_size, void* d_ws, size_t ws_size,
                              hipStream_t stream) {
  const float* x  = (const float*)d_in[0];
  const float* W1 = (const float*)d_in[1];
  const float* b1 = (const float*)d_in[2];
  const float* W2 = (const float*)d_in[3];
  const float* b2 = (const float*)d_in[4];
  const float* W3 = (const float*)d_in[5];
  const float* b3 = (const float*)d_in[6];
  float* out = (float*)d_out;

  char* ws = (char*)d_ws;
  u16* xb  = (u16*)ws;                                   // 1 MB
  u16* w1t = (u16*)(ws + (1u << 20));                    // 32 MB
  u16* w2t = (u16*)(ws + (1u << 20) + (32u << 20));      // 32 MB

  prepass_k <<<8704, 256, 0, stream>>>(W1, W2, w1t, w2t, x, xb);
  rf_main_k <<<4096, 512, 0, stream>>>(xb, w1t, w2t, b1, b2, W3, b3, out);
}

// Round 3
// 302.311 us; speedup vs baseline: 1.1347x; 1.1347x over previous
//
#include <hip/hip_runtime.h>

typedef unsigned short u16;
using u16x4  = __attribute__((ext_vector_type(4))) unsigned short;
using u16x8  = __attribute__((ext_vector_type(8))) unsigned short;
using bf16x8 = __attribute__((ext_vector_type(8))) short;
using f32x4  = __attribute__((ext_vector_type(4))) float;
using f32x16 = __attribute__((ext_vector_type(16))) float;

// ---------- helpers ----------
__device__ __forceinline__ u16 f2bf(float f) {
  union { float f; unsigned u; } v; v.f = f;
  unsigned r = v.u + 0x7FFFu + ((v.u >> 16) & 1u);  // RNE (inputs bounded, no NaN)
  return (u16)(r >> 16);
}

__device__ __forceinline__ unsigned cvt_pk_bf16(float a, float b) {
  unsigned d;
  asm("v_cvt_pk_bf16_f32 %0, %1, %2" : "=v"(d) : "v"(a), "v"(b));
  return d;  // low16 = bf16(a), high16 = bf16(b)
}

// ---------- fused pre-pass: W transpose+convert AND x convert ----------
// blocks 0..8191: W [mat][i][h] fp32 -> blocked bf16 [mat][i/16][h][16]
//   element (i,h) -> (i>>4)*4096 + h*16 + (i&15)
// blocks 8192..8703: x fp32 -> bf16
__global__ __launch_bounds__(256) void prepass_k(
    const float* __restrict__ W1, const float* __restrict__ W2,
    u16* __restrict__ w1t, u16* __restrict__ w2t,
    const float* __restrict__ x, u16* __restrict__ xb) {
  __shared__ float tile[64][65];
  const int bid = blockIdx.x;
  const int t = threadIdx.x;
  if (bid >= 8192) {                   // x conversion
    int i = (bid - 8192) * 256 + t;
    float4 v = ((const float4*)x)[i];
    u16x4 u;
    u.x = f2bf(v.x); u.y = f2bf(v.y); u.z = f2bf(v.z); u.w = f2bf(v.w);
    ((u16x4*)xb)[i] = u;
    return;
  }
  const int mat = bid >> 4;
  const int tl  = bid & 15;
  const int i0 = (tl >> 2) * 64, h0 = (tl & 3) * 64;
  const float* src = (mat < 256) ? (W1 + mat * 65536) : (W2 + (mat - 256) * 65536);
  u16*       dst   = (mat < 256) ? (w1t + mat * 65536) : (w2t + (mat - 256) * 65536);
#pragma unroll
  for (int j = 0; j < 4; ++j) {
    int lin = j * 256 + t;
    int row = lin >> 4, c4 = lin & 15;
    float4 v = *(const float4*)(src + (i0 + row) * 256 + h0 + c4 * 4);
    tile[row][c4 * 4 + 0] = v.x; tile[row][c4 * 4 + 1] = v.y;
    tile[row][c4 * 4 + 2] = v.z; tile[row][c4 * 4 + 3] = v.w;
  }
  __syncthreads();
  const int col = t >> 2;            // h = h0 + col
  const int kk  = (t & 3) * 8;       // 0,8,16,24
#pragma unroll
  for (int p = 0; p < 2; ++p) {
    u16x8 o;
#pragma unroll
    for (int jj = 0; jj < 8; ++jj)
      o[jj] = f2bf(tile[p * 32 + kk + jj][col]);
    *(u16x8*)(dst + ((i0 >> 4) + 2 * p + (kk >> 4)) * 4096 + (h0 + col) * 16 + (kk & 8)) = o;
  }
}

// ---------- main fused kernel: 256-row batch tile, 1 block/CU ----------
// Block = (subcarrier c, 256-row batch tile). 512 threads = 8 waves = 4 wq x 2 bh.
// Wave: 2 m-frags (m_base = wq*64, +0/+32) x 4 n-frags (rows bh*128 + nj*32).
// Per K-chunk per CU: MFMA 64 instr (~516 cyc), A-VMEM 16 KB (~256 cyc, halved vs r1
// because ONE c per CU), LDS-B 32 ds_read_b128 (~384 cyc) -> MFMA-bound on paper.
// K-loops are barrier-free; A (global) and B (LDS) both register-double-buffered
// one chunk ahead to cover L2 (~300cy) / LDS (~120cy) latency at 2 waves/SIMD.
// LDS = 256*264*2 = 132 KB (red aliased into sH after a barrier).
__global__ __launch_bounds__(512, 2) void rf_main_k(
    const u16* __restrict__ xb, const u16* __restrict__ w1t, const u16* __restrict__ w2t,
    const float* __restrict__ b1, const float* __restrict__ b2,
    const float* __restrict__ w3, const float* __restrict__ b3,
    float* __restrict__ out) {
  __shared__ u16 sH[256 * 264];        // x-tile, then H1 (in place), stride 264

  const int bid  = blockIdx.x;         // 2048 blocks
  const int xcd  = bid & 7;
  const int j8   = bid >> 3;           // 0..255
  const int c    = xcd * 32 + (j8 >> 3);
  const int b0   = (j8 & 7) * 256;
  const int t    = threadIdx.x;
  const int lane = t & 63;
  const int w    = t >> 6;
  const int l31  = lane & 31;
  const int hi   = lane >> 5;
  const bool hiH = hi != 0;
  const int wq   = w & 3;              // 4 m-positions
  const int bh   = w >> 2;             // 2 n-halves
  const int m_base = wq * 64;

  const u16* w1c = w1t + c * 65536;
  const u16* w2c = w2t + c * 65536;
  // A (weights, global): + ch*4096 + mi*512
  const int aoff = (m_base + l31) * 16 + hi * 8;
  // B (x/H1, LDS) per n-frag: + ch*16
  int bb[4];
#pragma unroll
  for (int nj = 0; nj < 4; ++nj)
    bb[nj] = (bh * 128 + nj * 32 + l31) * 264 + hi * 8;
  // wave-uniform column base for bias/w3 scalar loads
  const int bidx = __builtin_amdgcn_readfirstlane(c * 256 + m_base);

  f32x16 acc[2][4];
  bf16x8 aA[2], aB[2], bX[4], bY[4];

#define LOADA(dst, base)                                         \
  { dst[0] = *(const bf16x8*)(base);                             \
    dst[1] = *(const bf16x8*)((base) + 512); }

#define LOADB(dst, ch)                                           \
  { _Pragma("unroll")                                            \
    for (int _nj = 0; _nj < 4; ++_nj)                            \
      dst[_nj] = *(const bf16x8*)&sH[bb[_nj] + (ch) * 16]; }

#define COMPUTE(afr, bfr)                                        \
  { _Pragma("unroll")                                            \
    for (int _nj = 0; _nj < 4; ++_nj) {                          \
      acc[0][_nj] = __builtin_amdgcn_mfma_f32_32x32x16_bf16(afr[0], bfr[_nj], acc[0][_nj], 0, 0, 0); \
      acc[1][_nj] = __builtin_amdgcn_mfma_f32_32x32x16_bf16(afr[1], bfr[_nj], acc[1][_nj], 0, 0, 0); \
    } }

  // acc init = bias (wave-uniform per reg up to the hi/lo half-wave select)
#define INIT_ACC(bp)                                             \
  { _Pragma("unroll")                                            \
    for (int _mi = 0; _mi < 2; ++_mi) {                          \
      _Pragma("unroll")                                          \
      for (int _g = 0; _g < 4; ++_g) {                           \
        f32x4 _lo = *(const f32x4*)((bp) + bidx + _mi * 32 + _g * 8);     \
        f32x4 _h4 = *(const f32x4*)((bp) + bidx + _mi * 32 + _g * 8 + 4); \
        _Pragma("unroll")                                        \
        for (int _r = 0; _r < 4; ++_r) {                         \
          float _v = hiH ? _h4[_r] : _lo[_r];                    \
          _Pragma("unroll")                                      \
          for (int _nj = 0; _nj < 4; ++_nj)                      \
            acc[_mi][_nj][_g * 4 + _r] = _v;                     \
        } } } }

  // prefetch W1 chunk 0 while staging x
  LOADA(aA, w1c + aoff);

  // stage x-tile: 256 rows x 256 u16 -> sH stride 264
#pragma unroll
  for (int i = 0; i < 16; ++i) {
    int flat = i * 512 + t;
    int r = flat >> 5, s = flat & 31;
    u16x8 g = *(const u16x8*)(xb + (b0 + r) * 256 + s * 8);
    *(u16x8*)&sH[r * 264 + s * 8] = g;
  }
  INIT_ACC(b1);
  __syncthreads();

  // ========== Phase A: H1^T = W1^T . x^T (+b1, relu), barrier-free K-loop ==========
  LOADB(bX, 0);
#pragma unroll 1
  for (int ch = 0; ch < 16; ch += 2) {
    LOADA(aB, w1c + (ch + 1) * 4096 + aoff);
    LOADB(bY, ch + 1);
    COMPUTE(aA, bX);
    const u16* nxt = (ch == 14) ? (w2c + aoff)
                                : (w1c + (ch + 2) * 4096 + aoff);
    LOADA(aA, nxt);
    if (ch < 14) LOADB(bX, ch + 2);
    COMPUTE(aB, bY);
  }

  // Phase A epilogue: relu -> bf16 H1, in place over sX (b64 stores, in-lane packing)
  __syncthreads();                     // all x reads retired
#pragma unroll
  for (int nj = 0; nj < 4; ++nj) {
    const int row = bh * 128 + nj * 32 + l31;
#pragma unroll
    for (int mi = 0; mi < 2; ++mi)
#pragma unroll
      for (int g = 0; g < 4; ++g) {
        float v0 = fmaxf(acc[mi][nj][g * 4 + 0], 0.f);
        float v1 = fmaxf(acc[mi][nj][g * 4 + 1], 0.f);
        float v2 = fmaxf(acc[mi][nj][g * 4 + 2], 0.f);
        float v3 = fmaxf(acc[mi][nj][g * 4 + 3], 0.f);
        uint2 p;
        p.x = cvt_pk_bf16(v0, v1);
        p.y = cvt_pk_bf16(v2, v3);
        *(uint2*)&sH[row * 264 + m_base + mi * 32 + g * 8 + 4 * hi] = p;
      }
  }
  INIT_ACC(b2);
  __syncthreads();                     // H1 published

  // ========== Phase B: H2^T = W2^T . H1^T (+b2, relu), then in-lane dot W3 ==========
  LOADB(bX, 0);
#pragma unroll 1
  for (int ch = 0; ch < 16; ch += 2) {
    LOADA(aB, w2c + (ch + 1) * 4096 + aoff);
    LOADB(bY, ch + 1);
    COMPUTE(aA, bX);
    if (ch < 14) {
      LOADA(aA, w2c + (ch + 2) * 4096 + aoff);
      LOADB(bX, ch + 2);
    }
    COMPUTE(aB, bY);
  }

  // Phase B epilogue: out-col reduction fully in-lane (w3 wave-uniform per reg)
  float part[4] = {0.f, 0.f, 0.f, 0.f};
#pragma unroll
  for (int mi = 0; mi < 2; ++mi)
#pragma unroll
    for (int g = 0; g < 4; ++g) {
      f32x4 wlo = *(const f32x4*)(w3 + bidx + mi * 32 + g * 8);
      f32x4 whi = *(const f32x4*)(w3 + bidx + mi * 32 + g * 8 + 4);
#pragma unroll
      for (int r = 0; r < 4; ++r) {
        float wv = hiH ? whi[r] : wlo[r];
#pragma unroll
        for (int nj = 0; nj < 4; ++nj)
          part[nj] += fmaxf(acc[mi][nj][g * 4 + r], 0.f) * wv;
      }
    }
  __syncthreads();                     // all sH reads retired -> safe to alias red
  float* red = (float*)sH;             // 8 x 256 f32 = 8 KB, aliased into sH
#pragma unroll
  for (int nj = 0; nj < 4; ++nj)
    red[(wq * 2 + hi) * 256 + bh * 128 + nj * 32 + l31] = part[nj];
  __syncthreads();
  if (t < 256) {
    float v = b3[c];
#pragma unroll
    for (int k = 0; k < 8; ++k) v += red[k * 256 + t];
    out[(b0 + t) * 256 + c] = v;
  }
#undef LOADA
#undef LOADB
#undef COMPUTE
#undef INIT_ACC
}

// ---------- launcher ----------
extern "C" void kernel_launch(void* const* d_in, const int* in_sizes, int n_in,
                              void* d_out, int out_size, void* d_ws, size_t ws_size,
                              hipStream_t stream) {
  const float* x  = (const float*)d_in[0];
  const float* W1 = (const float*)d_in[1];
  const float* b1 = (const float*)d_in[2];
  const float* W2 = (const float*)d_in[3];
  const float* b2 = (const float*)d_in[4];
  const float* W3 = (const float*)d_in[5];
  const float* b3 = (const float*)d_in[6];
  float* out = (float*)d_out;

  char* ws = (char*)d_ws;
  u16* xb  = (u16*)ws;                                   // 1 MB
  u16* w1t = (u16*)(ws + (1u << 20));                    // 32 MB
  u16* w2t = (u16*)(ws + (1u << 20) + (32u << 20));      // 32 MB

  prepass_k <<<8704, 256, 0, stream>>>(W1, W2, w1t, w2t, x, xb);
  rf_main_k <<<2048, 512, 0, stream>>>(xb, w1t, w2t, b1, b2, W3, b3, out);
}

// Round 4
// 301.703 us; speedup vs baseline: 1.1370x; 1.0020x over previous
//
#include <hip/hip_runtime.h>

typedef unsigned short u16;
using u16x4  = __attribute__((ext_vector_type(4))) unsigned short;
using u16x8  = __attribute__((ext_vector_type(8))) unsigned short;
using bf16x8 = __attribute__((ext_vector_type(8))) short;
using f32x4  = __attribute__((ext_vector_type(4))) float;
using f32x16 = __attribute__((ext_vector_type(16))) float;

// ---------- helpers ----------
__device__ __forceinline__ u16 f2bf(float f) {
  union { float f; unsigned u; } v; v.f = f;
  unsigned r = v.u + 0x7FFFu + ((v.u >> 16) & 1u);  // RNE (inputs bounded, no NaN)
  return (u16)(r >> 16);
}

__device__ __forceinline__ unsigned cvt_pk_bf16(float a, float b) {
  unsigned d;
  asm("v_cvt_pk_bf16_f32 %0, %1, %2" : "=v"(d) : "v"(a), "v"(b));
  return d;  // low16 = bf16(a), high16 = bf16(b)
}

// ---------- fused pre-pass: W transpose+convert AND x convert ----------
// blocks 0..8191: W [mat][i][h] fp32 -> blocked bf16 [mat][i/16][h][16]
//   element (i,h) -> (i>>4)*4096 + h*16 + (i&15)
// blocks 8192..8703: x fp32 -> bf16
__global__ __launch_bounds__(256) void prepass_k(
    const float* __restrict__ W1, const float* __restrict__ W2,
    u16* __restrict__ w1t, u16* __restrict__ w2t,
    const float* __restrict__ x, u16* __restrict__ xb) {
  __shared__ float tile[64][65];
  const int bid = blockIdx.x;
  const int t = threadIdx.x;
  if (bid >= 8192) {                   // x conversion
    int i = (bid - 8192) * 256 + t;
    float4 v = ((const float4*)x)[i];
    u16x4 u;
    u.x = f2bf(v.x); u.y = f2bf(v.y); u.z = f2bf(v.z); u.w = f2bf(v.w);
    ((u16x4*)xb)[i] = u;
    return;
  }
  const int mat = bid >> 4;
  const int tl  = bid & 15;
  const int i0 = (tl >> 2) * 64, h0 = (tl & 3) * 64;
  const float* src = (mat < 256) ? (W1 + mat * 65536) : (W2 + (mat - 256) * 65536);
  u16*       dst   = (mat < 256) ? (w1t + mat * 65536) : (w2t + (mat - 256) * 65536);
#pragma unroll
  for (int j = 0; j < 4; ++j) {
    int lin = j * 256 + t;
    int row = lin >> 4, c4 = lin & 15;
    float4 v = *(const float4*)(src + (i0 + row) * 256 + h0 + c4 * 4);
    tile[row][c4 * 4 + 0] = v.x; tile[row][c4 * 4 + 1] = v.y;
    tile[row][c4 * 4 + 2] = v.z; tile[row][c4 * 4 + 3] = v.w;
  }
  __syncthreads();
  const int col = t >> 2;            // h = h0 + col
  const int kk  = (t & 3) * 8;       // 0,8,16,24
#pragma unroll
  for (int p = 0; p < 2; ++p) {
    u16x8 o;
#pragma unroll
    for (int jj = 0; jj < 8; ++jj)
      o[jj] = f2bf(tile[p * 32 + kk + jj][col]);
    *(u16x8*)(dst + ((i0 >> 4) + 2 * p + (kk >> 4)) * 4096 + (h0 + col) * 16 + (kk & 8)) = o;
  }
}

// ---------- main fused kernel: 256-row tile, 1 block/CU, deep reg pipeline ----------
// Block = (subcarrier c, 256-row batch tile). 512 threads = 8 waves = 4 wq x 2 bh.
// Wave: 2 m-frags (m_base = wq*64, +0/+32) x 4 n-frags (rows bh*128 + nj*32).
// Per K-chunk per CU: MFMA 64 (~516 cyc) vs A-VMEM 16 KB (~256) vs LDS-B 32 b128 (~384).
// At 2 waves/SIMD the TLP can't hide A's ~200-300cy L2 latency -> deep ILP pipeline:
//  - K-loop fully unrolled; A kept 3 chunks ahead (4 rotating reg sets, compile-time
//    indices), B 1 chunk ahead (2 sets). Compiler emits counted vmcnt/lgkm waits.
//  - Phase-B bias folded into the epilogue so the phase boundary doesn't drain the
//    in-flight W2 prefetch.
// Regs: 128 acc + 32 A + 32 B + addressing ~= 245 <= 256 -> keeps 2 waves/SIMD.
__global__ __launch_bounds__(512, 2) void rf_main_k(
    const u16* __restrict__ xb, const u16* __restrict__ w1t, const u16* __restrict__ w2t,
    const float* __restrict__ b1, const float* __restrict__ b2,
    const float* __restrict__ w3, const float* __restrict__ b3,
    float* __restrict__ out) {
  __shared__ u16 sH[256 * 264];        // x-tile, then H1 (in place), stride 264

  const int bid  = blockIdx.x;         // 2048 blocks
  const int xcd  = bid & 7;
  const int j8   = bid >> 3;           // 0..255
  const int c    = xcd * 32 + (j8 >> 3);
  const int b0   = (j8 & 7) * 256;
  const int t    = threadIdx.x;
  const int lane = t & 63;
  const int w    = t >> 6;
  const int l31  = lane & 31;
  const int hi   = lane >> 5;
  const bool hiH = hi != 0;
  const int wq   = w & 3;              // 4 m-positions
  const int bh   = w >> 2;             // 2 n-halves
  const int m_base = wq * 64;

  const u16* w1c = w1t + c * 65536;
  const u16* w2c = w2t + c * 65536;
  const int aoff = (m_base + l31) * 16 + hi * 8;     // + ch*4096 + mi*512
  int bb[4];
#pragma unroll
  for (int nj = 0; nj < 4; ++nj)
    bb[nj] = (bh * 128 + nj * 32 + l31) * 264 + hi * 8;   // + ch*16
  const int bidx = __builtin_amdgcn_readfirstlane(c * 256 + m_base);

  f32x16 acc[2][4];
  bf16x8 aS[4][2];                     // A rotating sets (ch & 3), depth 3
  bf16x8 bS[2][4];                     // B rotating sets (ch & 1), depth 1

#define LOADA(dst, base)                                         \
  { dst[0] = *(const bf16x8*)(base);                             \
    dst[1] = *(const bf16x8*)((base) + 512); }

#define LOADB(dst, ch)                                           \
  { _Pragma("unroll")                                            \
    for (int _nj = 0; _nj < 4; ++_nj)                            \
      dst[_nj] = *(const bf16x8*)&sH[bb[_nj] + (ch) * 16]; }

#define COMPUTE(afr, bfr)                                        \
  { _Pragma("unroll")                                            \
    for (int _nj = 0; _nj < 4; ++_nj) {                          \
      acc[0][_nj] = __builtin_amdgcn_mfma_f32_32x32x16_bf16(afr[0], bfr[_nj], acc[0][_nj], 0, 0, 0); \
      acc[1][_nj] = __builtin_amdgcn_mfma_f32_32x32x16_bf16(afr[1], bfr[_nj], acc[1][_nj], 0, 0, 0); \
    } }

  // ---- prologue: A chunks 0..2 in flight, stage x, bias-init acc (phase A only) ----
  LOADA(aS[0], w1c + 0 * 4096 + aoff);
  LOADA(aS[1], w1c + 1 * 4096 + aoff);
  LOADA(aS[2], w1c + 2 * 4096 + aoff);

#pragma unroll
  for (int i = 0; i < 16; ++i) {
    int flat = i * 512 + t;
    int r = flat >> 5, s = flat & 31;
    u16x8 g = *(const u16x8*)(xb + (b0 + r) * 256 + s * 8);
    *(u16x8*)&sH[r * 264 + s * 8] = g;
  }
  // acc init = b1 bias (wave-uniform per reg up to the hi/lo half-wave select)
#pragma unroll
  for (int mi = 0; mi < 2; ++mi)
#pragma unroll
    for (int g = 0; g < 4; ++g) {
      f32x4 lo = *(const f32x4*)(b1 + bidx + mi * 32 + g * 8);
      f32x4 h4 = *(const f32x4*)(b1 + bidx + mi * 32 + g * 8 + 4);
#pragma unroll
      for (int r = 0; r < 4; ++r) {
        float v = hiH ? h4[r] : lo[r];
#pragma unroll
        for (int nj = 0; nj < 4; ++nj)
          acc[mi][nj][g * 4 + r] = v;
      }
    }
  __syncthreads();

  // ========== Phase A: H1^T = W1^T . x^T (+b1, relu) ==========
  LOADB(bS[0], 0);
#pragma unroll
  for (int ch = 0; ch < 16; ++ch) {
    // A(ch+3): last 3 iterations prefetch W2 chunks 0..2
    const u16* ab = (ch + 3 < 16) ? (w1c + (ch + 3) * 4096) : (w2c + (ch - 13) * 4096);
    LOADA(aS[(ch + 3) & 3], ab + aoff);
    if (ch + 1 < 16) LOADB(bS[(ch + 1) & 1], ch + 1);
    COMPUTE(aS[ch & 3], bS[ch & 1]);
  }

  // Phase A epilogue: relu -> bf16 H1, in place over sX (b64 stores, in-lane packing)
  __syncthreads();                     // all x reads retired
#pragma unroll
  for (int nj = 0; nj < 4; ++nj) {
    const int row = bh * 128 + nj * 32 + l31;
#pragma unroll
    for (int mi = 0; mi < 2; ++mi)
#pragma unroll
      for (int g = 0; g < 4; ++g) {
        float v0 = fmaxf(acc[mi][nj][g * 4 + 0], 0.f);
        float v1 = fmaxf(acc[mi][nj][g * 4 + 1], 0.f);
        float v2 = fmaxf(acc[mi][nj][g * 4 + 2], 0.f);
        float v3 = fmaxf(acc[mi][nj][g * 4 + 3], 0.f);
        uint2 p;
        p.x = cvt_pk_bf16(v0, v1);
        p.y = cvt_pk_bf16(v2, v3);
        *(uint2*)&sH[row * 264 + m_base + mi * 32 + g * 8 + 4 * hi] = p;
        acc[mi][nj][g * 4 + 0] = 0.f; acc[mi][nj][g * 4 + 1] = 0.f;
        acc[mi][nj][g * 4 + 2] = 0.f; acc[mi][nj][g * 4 + 3] = 0.f;
      }
  }
  __syncthreads();                     // H1 published

  // ========== Phase B: H2^T = W2^T . H1^T, bias+relu+dot(W3) in epilogue ==========
  LOADB(bS[0], 0);
#pragma unroll
  for (int ch = 0; ch < 16; ++ch) {
    if (ch + 3 < 16) LOADA(aS[(ch + 3) & 3], w2c + (ch + 3) * 4096 + aoff);
    if (ch + 1 < 16) LOADB(bS[(ch + 1) & 1], ch + 1);
    COMPUTE(aS[ch & 3], bS[ch & 1]);
  }

  // Phase B epilogue: out-col reduction fully in-lane (b2/w3 wave-uniform per reg)
  float part[4] = {0.f, 0.f, 0.f, 0.f};
#pragma unroll
  for (int mi = 0; mi < 2; ++mi)
#pragma unroll
    for (int g = 0; g < 4; ++g) {
      f32x4 blo = *(const f32x4*)(b2 + bidx + mi * 32 + g * 8);
      f32x4 bh4 = *(const f32x4*)(b2 + bidx + mi * 32 + g * 8 + 4);
      f32x4 wlo = *(const f32x4*)(w3 + bidx + mi * 32 + g * 8);
      f32x4 wh4 = *(const f32x4*)(w3 + bidx + mi * 32 + g * 8 + 4);
#pragma unroll
      for (int r = 0; r < 4; ++r) {
        float bv = hiH ? bh4[r] : blo[r];
        float wv = hiH ? wh4[r] : wlo[r];
#pragma unroll
        for (int nj = 0; nj < 4; ++nj)
          part[nj] += fmaxf(acc[mi][nj][g * 4 + r] + bv, 0.f) * wv;
      }
    }
  __syncthreads();                     // all sH reads retired -> safe to alias red
  float* red = (float*)sH;             // 8 x 256 f32 = 8 KB, aliased into sH
#pragma unroll
  for (int nj = 0; nj < 4; ++nj)
    red[(wq * 2 + hi) * 256 + bh * 128 + nj * 32 + l31] = part[nj];
  __syncthreads();
  if (t < 256) {
    float v = b3[c];
#pragma unroll
    for (int k = 0; k < 8; ++k) v += red[k * 256 + t];
    out[(b0 + t) * 256 + c] = v;
  }
#undef LOADA
#undef LOADB
#undef COMPUTE
}

// ---------- launcher ----------
extern "C" void kernel_launch(void* const* d_in, const int* in_sizes, int n_in,
                              void* d_out, int out_size, void* d_ws, size_t ws_size,
                              hipStream_t stream) {
  const float* x  = (const float*)d_in[0];
  const float* W1 = (const float*)d_in[1];
  const float* b1 = (const float*)d_in[2];
  const float* W2 = (const float*)d_in[3];
  const float* b2 = (const float*)d_in[4];
  const float* W3 = (const float*)d_in[5];
  const float* b3 = (const float*)d_in[6];
  float* out = (float*)d_out;

  char* ws = (char*)d_ws;
  u16* xb  = (u16*)ws;                                   // 1 MB
  u16* w1t = (u16*)(ws + (1u << 20));                    // 32 MB
  u16* w2t = (u16*)(ws + (1u << 20) + (32u << 20));      // 32 MB

  prepass_k <<<8704, 256, 0, stream>>>(W1, W2, w1t, w2t, x, xb);
  rf_main_k <<<2048, 512, 0, stream>>>(xb, w1t, w2t, b1, b2, W3, b3, out);
}